// Round 3
// baseline (238.121 us; speedup 1.0000x reference)
//
#include <hip/hip_runtime.h>

// De-emphasis IIR: y[n] = 0.95*y[n-1] + x[n], rows of 524288 f32.
// Wave-autonomous blocked scan: each 64-lane wave owns a 2048-float chunk
// with a 256-float halo (0.95^256 ~ 2e-6 truncation, far below threshold).
// No LDS, no barriers: halo IC via weighted shuffle-reduce, cross-lane
// carry via geometric-weight Hillis-Steele shuffle scan (ratio 0.95^32).
// Lane l holds floats [32l, 32l+32) of its chunk in 8 float4 registers;
// lane stride = 128 B = one full L2 line per lane, so direct global
// loads/stores generate no HBM over-traffic (L1 absorbs the 4x per-line
// instruction reuse).

#define T_LEN   524288
#define WCHUNK  2048              // floats per wave
#define HALO    256               // floats of look-back
#define CPR     (T_LEN / WCHUNK)  // 256 chunks per row
#define L2C95   (-0.07400058f)    // log2(0.95)
#define C32     (0.19371149f)     // 0.95^32

__global__ __launch_bounds__(256, 8)
void deemph_kernel(const float4* __restrict__ xin, float4* __restrict__ yout) {
    const int lane = threadIdx.x & 63;
    const int wv   = threadIdx.x >> 6;
    const int g    = blockIdx.x * 4 + wv;        // global wave id
    const int row  = g >> 8;                     // 256 waves per row
    const int ck   = g & (CPR - 1);

    const int row4   = row * (T_LEN / 4);
    const int cbase4 = ck * (WCHUNK / 4);
    const int base4  = row4 + cbase4;

    // ---- halo: IC = sum_{j<256} 0.95^j * x[cstart-1-j] (wave-uniform) ----
    float IC = 0.f;
    if (ck != 0) {
        const float4 h = xin[base4 - (HALO / 4) + lane];   // coalesced 1 KB
        float hl = h.x;
        hl = fmaf(0.95f, hl, h.y);
        hl = fmaf(0.95f, hl, h.z);
        hl = fmaf(0.95f, hl, h.w);
        // lane l's 4 floats end 4*(63-l) samples before the chunk start
        float t = hl * exp2f((float)(4 * (63 - lane)) * L2C95);
        #pragma unroll
        for (int d = 1; d < 64; d <<= 1) t += __shfl_xor(t, d, 64);
        IC = t;
    }

    // ---- load lane's 32 floats (8 float4, one 128B line per lane) ----
    const float4* __restrict__ src = xin + base4 + lane * 8;
    float4 q[8];
    #pragma unroll
    for (int k = 0; k < 8; ++k) q[k] = src[k];

    // ---- pass A: local scan final (zero IC) ----
    float f = 0.f;
    #pragma unroll
    for (int k = 0; k < 8; ++k) {
        f = fmaf(0.95f, f, q[k].x);
        f = fmaf(0.95f, f, q[k].y);
        f = fmaf(0.95f, f, q[k].z);
        f = fmaf(0.95f, f, q[k].w);
    }

    // ---- cross-lane carry: Hillis-Steele with geometric weight c32^d ----
    float y = f;
    float m = C32;
    #pragma unroll
    for (int d = 1; d < 64; d <<= 1) {
        const float up = __shfl_up(y, d, 64);
        if (lane >= d) y = fmaf(m, up, y);
        m = m * m;
    }
    const float yup = __shfl_up(y, 1, 64);
    // carry into lane's first sample: previous lanes' finals + decayed IC
    const float E = ((lane > 0) ? yup : 0.f)
                  + exp2f((float)(32 * lane) * L2C95) * IC;

    // ---- pass B: true outputs, store fused ----
    float4* __restrict__ dst = yout + base4 + lane * 8;
    float yy = E;
    #pragma unroll
    for (int k = 0; k < 8; ++k) {
        float4 v = q[k];
        yy = fmaf(0.95f, yy, v.x); v.x = yy;
        yy = fmaf(0.95f, yy, v.y); v.y = yy;
        yy = fmaf(0.95f, yy, v.z); v.z = yy;
        yy = fmaf(0.95f, yy, v.w); v.w = yy;
        dst[k] = v;
    }
}

extern "C" void kernel_launch(void* const* d_in, const int* in_sizes, int n_in,
                              void* d_out, int out_size, void* d_ws, size_t ws_size,
                              hipStream_t stream) {
    const float4* xin  = (const float4*)d_in[0];
    float4*       yout = (float4*)d_out;
    const int rows   = in_sizes[0] / T_LEN;               // 64
    const int waves  = rows * CPR;                        // 16384
    const int blocks = waves / 4;                         // 4096 x 256 threads
    deemph_kernel<<<dim3(blocks), dim3(256), 0, stream>>>(xin, yout);
}

// Round 5
// 228.661 us; speedup vs baseline: 1.0414x; 1.0414x over previous
//
#include <hip/hip_runtime.h>

// De-emphasis IIR: y[n] = 0.95*y[n-1] + x[n], rows of 524288 f32.
// Round-4 structure: wave-autonomous, FULLY COALESCED, zero LDS/barriers.
// Each wave owns 2048 contiguous floats, processed as 8 serial tiles of
// 256 floats. Per tile: one coalesced float4 load (lane l <-> f4 slot l),
// in-register 4-FMA local scan, 6-step geometric Hillis-Steele shuffle scan
// (ratio 0.95^4), coalesced float4 store. Tile->tile carry via lane-63
// broadcast (exact). Initial condition from one extra halo tile (256-sample
// truncation: 0.95^256 ~ 2e-6 relative, far below the 0.37 threshold).
// All 9 tile loads are address-independent and issued upfront -> MLP covers
// HBM latency; the serial shuffle chain hides under 8 waves/SIMD.

#define T_LEN   524288
#define WCHUNK  2048              // floats per wave
#define NT      8                 // tiles per wave chunk
#define CPR     (T_LEN / WCHUNK)  // 256 chunks per row
#define L2C95   (-0.07400058f)    // log2(0.95)
#define C4      (0.81450625f)     // 0.95^4
#define C256    (1.9875265e-6f)   // 0.95^256

__global__ __launch_bounds__(256, 8)
void deemph_kernel(const float4* __restrict__ xin, float4* __restrict__ yout) {
    const int lane = threadIdx.x & 63;
    const int wv   = threadIdx.x >> 6;
    const int g    = blockIdx.x * 4 + wv;     // global wave id
    const int row  = g >> 8;                  // 256 waves per row
    const int ck   = g & (CPR - 1);

    const int base4 = row * (T_LEN / 4) + ck * (WCHUNK / 4);

    // ---- issue ALL loads upfront (independent addresses -> full MLP) ----
    float4 h;
    if (ck != 0) h = xin[base4 - 64 + lane];
    else         h = make_float4(0.f, 0.f, 0.f, 0.f);
    float4 q[NT];
    #pragma unroll
    for (int k = 0; k < NT; ++k) q[k] = xin[base4 + 64 * k + lane];

    // per-lane decay weight for carry-in: 0.95^(4*lane)
    const float wl = exp2f((float)(4 * lane) * L2C95);

    // ---- halo tile: scan (no store) to produce the chunk's IC ----
    float Y;
    {
        float f = h.x;
        f = fmaf(0.95f, f, h.y);
        f = fmaf(0.95f, f, h.z);
        f = fmaf(0.95f, f, h.w);
        float y = f, m = C4;
        #pragma unroll
        for (int d = 1; d < 64; d <<= 1) {
            const float up = __shfl_up(y, d, 64);
            if (lane >= d) y = fmaf(m, up, y);
            m = m * m;
        }
        Y = __shfl(y, 63, 64);               // value at sample -1 of the chunk
    }

    // ---- 8 tiles: local scan, cross-lane scan, apply carry, store ----
    #pragma unroll
    for (int k = 0; k < NT; ++k) {
        float4 v = q[k];
        float f = v.x;
        f = fmaf(0.95f, f, v.y);
        f = fmaf(0.95f, f, v.z);
        f = fmaf(0.95f, f, v.w);
        float y = f, m = C4;
        #pragma unroll
        for (int d = 1; d < 64; d <<= 1) {
            const float up = __shfl_up(y, d, 64);
            if (lane >= d) y = fmaf(m, up, y);
            m = m * m;
        }
        const float yup = __shfl_up(y, 1, 64);
        // carry into lane's first sample: prev lanes' final + decayed tile IC
        float yy = ((lane > 0) ? yup : 0.f) + wl * Y;
        yy = fmaf(0.95f, yy, v.x); v.x = yy;
        yy = fmaf(0.95f, yy, v.y); v.y = yy;
        yy = fmaf(0.95f, yy, v.z); v.z = yy;
        yy = fmaf(0.95f, yy, v.w); v.w = yy;
        yout[base4 + 64 * k + lane] = v;
        // next tile's IC: lane-63 true final = y_63 + 0.95^256 * Y
        Y = fmaf(C256, Y, __shfl(y, 63, 64));
    }
}

extern "C" void kernel_launch(void* const* d_in, const int* in_sizes, int n_in,
                              void* d_out, int out_size, void* d_ws, size_t ws_size,
                              hipStream_t stream) {
    const float4* xin  = (const float4*)d_in[0];
    float4*       yout = (float4*)d_out;
    const int rows   = in_sizes[0] / T_LEN;   // 64
    const int waves  = rows * CPR;            // 16384
    const int blocks = waves / 4;             // 4096 x 256 threads
    deemph_kernel<<<dim3(blocks), dim3(256), 0, stream>>>(xin, yout);
}